// Round 2
// baseline (994.733 us; speedup 1.0000x reference)
//
#include <hip/hip_runtime.h>
#include <math.h>

// Problem constants
#define Bq 4
#define Lq 2048
#define BLq 8192          // B*L
#define DMq 128           // d_model
#define DIq 256           // d_inner
#define DSq 16            // d_state
#define NCq 16            // scan chunks
#define TCq 128           // chunk length (NCq*TCq == Lq)

__device__ __forceinline__ float siluf(float x){ return x / (1.f + expf(-x)); }
__device__ __forceinline__ float softplusf(float x){
  return (x > 0.f) ? (x + log1pf(expf(-x))) : log1pf(expf(x));
}

// h[bl,e] = sum_k x[bl,k]*W[k,e] + b[e]   (K=64, N=128)
__global__ __launch_bounds__(128) void k_embed(const float* __restrict__ x,
    const float* __restrict__ W, const float* __restrict__ bb, float* __restrict__ h){
  int bl = blockIdx.x; int e = threadIdx.x;
  __shared__ float xs[64];
  if (e < 64) xs[e] = x[(size_t)bl*64 + e];
  __syncthreads();
  float acc = bb[e];
  #pragma unroll
  for (int k=0;k<64;k++) acc = fmaf(xs[k], W[k*128 + e], acc);
  h[(size_t)bl*128 + e] = acc;
}

// C[M,N] = A[M,K] @ W[N,K]^T. BM=BN=64, BK=16, 256 thr, 4x4 per thread.
__global__ __launch_bounds__(256) void k_gemm_bt(const float* __restrict__ A,
    const float* __restrict__ W, float* __restrict__ C, int M, int N, int K){
  __shared__ float As[16][68];   // stride 68 floats = 272B (16B aligned, conflict-safe)
  __shared__ float Ws[16][68];
  const int tid = threadIdx.x;
  const int tx = tid & 15, ty = tid >> 4;
  const int lr = tid >> 2, lc = (tid & 3) << 2;
  const int m0 = blockIdx.x << 6, n0 = blockIdx.y << 6;
  float acc[4][4] = {};
  for (int k0 = 0; k0 < K; k0 += 16){
    float4 av = *(const float4*)(A + (size_t)(m0+lr)*K + k0 + lc);
    float4 wv = *(const float4*)(W + (size_t)(n0+lr)*K + k0 + lc);
    As[lc+0][lr]=av.x; As[lc+1][lr]=av.y; As[lc+2][lr]=av.z; As[lc+3][lr]=av.w;
    Ws[lc+0][lr]=wv.x; Ws[lc+1][lr]=wv.y; Ws[lc+2][lr]=wv.z; Ws[lc+3][lr]=wv.w;
    __syncthreads();
    #pragma unroll
    for (int k=0;k<16;k++){
      float4 a = *(const float4*)&As[k][ty<<2];
      float4 w = *(const float4*)&Ws[k][tx<<2];
      acc[0][0]=fmaf(a.x,w.x,acc[0][0]); acc[0][1]=fmaf(a.x,w.y,acc[0][1]);
      acc[0][2]=fmaf(a.x,w.z,acc[0][2]); acc[0][3]=fmaf(a.x,w.w,acc[0][3]);
      acc[1][0]=fmaf(a.y,w.x,acc[1][0]); acc[1][1]=fmaf(a.y,w.y,acc[1][1]);
      acc[1][2]=fmaf(a.y,w.z,acc[1][2]); acc[1][3]=fmaf(a.y,w.w,acc[1][3]);
      acc[2][0]=fmaf(a.z,w.x,acc[2][0]); acc[2][1]=fmaf(a.z,w.y,acc[2][1]);
      acc[2][2]=fmaf(a.z,w.z,acc[2][2]); acc[2][3]=fmaf(a.z,w.w,acc[2][3]);
      acc[3][0]=fmaf(a.w,w.x,acc[3][0]); acc[3][1]=fmaf(a.w,w.y,acc[3][1]);
      acc[3][2]=fmaf(a.w,w.z,acc[3][2]); acc[3][3]=fmaf(a.w,w.w,acc[3][3]);
    }
    __syncthreads();
  }
  #pragma unroll
  for (int i=0;i<4;i++){
    float4 o = make_float4(acc[i][0],acc[i][1],acc[i][2],acc[i][3]);
    *(float4*)(C + (size_t)(m0+(ty<<2)+i)*N + n0 + (tx<<2)) = o;
  }
}

// causal depthwise conv (D_CONV=4) over u-half of xz, then SiLU -> u
__global__ __launch_bounds__(256) void k_conv(const float* __restrict__ xz,
    const float* __restrict__ cw, const float* __restrict__ cb, float* __restrict__ u){
  int bl = blockIdx.x; int l = bl & 2047; int d = threadIdx.x;
  float4 w = *(const float4*)(cw + d*4);
  float wv[4] = {w.x, w.y, w.z, w.w};
  const float* base = xz + (size_t)bl*512 + d;
  float acc = cb[d];
  #pragma unroll
  for (int j=0;j<4;j++){
    if (l-3+j >= 0) acc = fmaf(base[(j-3)*512], wv[j], acc);
  }
  u[(size_t)bl*256 + d] = siluf(acc);
}

// per (b,l): x_dbl[40] = u_row @ xp_w^T ; delta[256]=softplus(x_dbl[:8]@dt_w^T+dt_b);
// Bm,Cm -> bc[32]. 64 threads: 8 groups x 8 lanes; group g owns e=g*5..g*5+4.
__global__ __launch_bounds__(64) void k_xdbl(const float* __restrict__ u,
    const float* __restrict__ xpw, const float* __restrict__ dtw,
    const float* __restrict__ dtb, float* __restrict__ dlt, float* __restrict__ bc){
  int bl = blockIdx.x; int tid = threadIdx.x;
  int g = tid >> 3, i = tid & 7;
  float4 us[8];
  #pragma unroll
  for (int j=0;j<8;j++) us[j] = *(const float4*)(u + (size_t)bl*256 + i*32 + j*4);
  __shared__ float xd[40];
  #pragma unroll
  for (int q=0;q<5;q++){
    int e = g*5 + q;
    const float* wp = xpw + e*256 + i*32;
    float p = 0.f;
    #pragma unroll
    for (int j=0;j<8;j++){
      float4 w = *(const float4*)(wp + j*4);
      p = fmaf(us[j].x,w.x,p); p = fmaf(us[j].y,w.y,p);
      p = fmaf(us[j].z,w.z,p); p = fmaf(us[j].w,w.w,p);
    }
    p += __shfl_xor(p,1); p += __shfl_xor(p,2); p += __shfl_xor(p,4);
    if (i==0) xd[e] = p;
  }
  __syncthreads();
  if (tid < 32) bc[(size_t)bl*32 + tid] = xd[8+tid];
  float xr[8];
  #pragma unroll
  for (int r=0;r<8;r++) xr[r] = xd[r];
  float o4[4];
  #pragma unroll
  for (int c=0;c<4;c++){
    int d = tid*4 + c;
    float acc = dtb[d];
    const float* wp = dtw + d*8;
    #pragma unroll
    for (int r=0;r<8;r++) acc = fmaf(xr[r], wp[r], acc);
    o4[c] = softplusf(acc);
  }
  *(float4*)(dlt + (size_t)bl*256 + tid*4) = make_float4(o4[0],o4[1],o4[2],o4[3]);
}

// scan pass A: per chunk local scan from 0 -> final local state + sum(delta)
__global__ __launch_bounds__(256) void k_scan_a(const float* __restrict__ dlt,
    const float* __restrict__ u, const float* __restrict__ bc,
    const float* __restrict__ alog, float* __restrict__ sf, float* __restrict__ sd){
  int c = blockIdx.x, dg = blockIdx.y, b = blockIdx.z;
  int tid = threadIdx.x; int n = tid & 15, dlc = tid >> 4; int d = dg*16 + dlc;
  float Av = -expf(alog[d*16+n]);
  size_t row0 = (size_t)b*Lq + (size_t)c*TCq;
  const float* dp = dlt + row0*256 + d;
  const float* up = u   + row0*256 + d;
  const float* Bp = bc  + row0*32 + n;
  float s = 0.f, sdl = 0.f;
  for (int t=0;t<TCq;t++){
    float de = dp[t*256];
    float uu = up[t*256];
    float Bv = Bp[t*32];
    s = fmaf(expf(de*Av), s, de*uu*Bv);
    sdl += de;
  }
  size_t idx = ((size_t)b*NCq + c)*256 + d;
  sf[idx*16 + n] = s;
  if (n==0) sd[idx] = sdl;
}

// scan pass B: combine chunk aggregates -> true initial state per chunk (exclusive)
__global__ __launch_bounds__(256) void k_scan_b(const float* __restrict__ sf,
    const float* __restrict__ sd, const float* __restrict__ alog, float* __restrict__ si){
  int b = blockIdx.x >> 4, dg = blockIdx.x & 15;
  int tid = threadIdx.x; int n = tid & 15, dlc = tid >> 4; int d = dg*16 + dlc;
  float Av = -expf(alog[d*16+n]);
  float s = 0.f;
  for (int c=0;c<NCq;c++){
    size_t idx = ((size_t)b*NCq + c)*256 + d;
    si[idx*16+n] = s;
    s = sf[idx*16+n] + expf(Av * sd[idx]) * s;
  }
}

// scan pass C: re-scan chunk from true init, fused epilogue y=(sum_n sC + uD)*silu(z)
__global__ __launch_bounds__(256) void k_scan_c(const float* __restrict__ dlt,
    const float* __restrict__ u, const float* __restrict__ bc,
    const float* __restrict__ xz, const float* __restrict__ si,
    const float* __restrict__ alog, const float* __restrict__ dsk, float* __restrict__ y){
  int c = blockIdx.x, dg = blockIdx.y, b = blockIdx.z;
  int tid = threadIdx.x; int n = tid & 15, dlc = tid >> 4; int d = dg*16 + dlc;
  float Av = -expf(alog[d*16+n]);
  float Dv = dsk[d];
  size_t row0 = (size_t)b*Lq + (size_t)c*TCq;
  const float* dp = dlt + row0*256 + d;
  const float* up = u   + row0*256 + d;
  const float* Bp = bc  + row0*32 + n;
  const float* Cp = bc  + row0*32 + 16 + n;
  const float* zp = xz  + row0*512 + 256 + d;
  float* yp = y + row0*256 + d;
  float s = si[(((size_t)b*NCq + c)*256 + d)*16 + n];
  for (int t=0;t<TCq;t++){
    float de = dp[t*256], uu = up[t*256], Bv = Bp[t*32], Cv = Cp[t*32], zz = zp[t*512];
    s = fmaf(expf(de*Av), s, de*uu*Bv);
    float py = s*Cv;
    py += __shfl_xor(py,1); py += __shfl_xor(py,2);
    py += __shfl_xor(py,4); py += __shfl_xor(py,8);
    if (n==0) yp[t*256] = (py + uu*Dv) * siluf(zz);
  }
}

// mean over L then latent GEMV: out[b,:] = pooled @ W_lat + b_lat
__global__ __launch_bounds__(1024) void k_pool(const float* __restrict__ h,
    const float* __restrict__ Wl, const float* __restrict__ bl_, float* __restrict__ out){
  int b = blockIdx.x; int tid = threadIdx.x;
  int e = tid & 127, st = tid >> 7;   // 8 stripes of 256 rows
  float s = 0.f;
  for (int l = st*256; l < st*256 + 256; ++l) s += h[((size_t)b*2048 + l)*128 + e];
  __shared__ float part[8][128];
  __shared__ float pooled[128];
  part[st][e] = s;
  __syncthreads();
  if (tid < 128){
    float tot = 0.f;
    #pragma unroll
    for (int j=0;j<8;j++) tot += part[j][tid];
    pooled[tid] = tot * (1.f/2048.f);
  }
  __syncthreads();
  if (tid < 128){
    float acc = bl_[tid];
    for (int e2=0;e2<128;e2++) acc = fmaf(pooled[e2], Wl[e2*128 + tid], acc);
    out[b*128 + tid] = acc;
  }
}

extern "C" void kernel_launch(void* const* d_in, const int* in_sizes, int n_in,
                              void* d_out, int out_size, void* d_ws, size_t ws_size,
                              hipStream_t stream){
  const float* x    = (const float*)d_in[0];
  const float* Wem  = (const float*)d_in[1];
  const float* bem  = (const float*)d_in[2];
  const float* inw  = (const float*)d_in[3];
  const float* cw   = (const float*)d_in[4];
  const float* cb   = (const float*)d_in[5];
  const float* xpw  = (const float*)d_in[6];
  const float* dtw  = (const float*)d_in[7];
  const float* dtb  = (const float*)d_in[8];
  const float* alog = (const float*)d_in[9];
  const float* dsk  = (const float*)d_in[10];
  const float* outw = (const float*)d_in[11];
  const float* Wl   = (const float*)d_in[12];
  const float* bl_  = (const float*)d_in[13];
  float* out = (float*)d_out;

  float* p  = (float*)d_ws;
  float* h  = p;  p += (size_t)BLq*128;
  float* xz = p;  p += (size_t)BLq*512;
  float* u  = p;  p += (size_t)BLq*256;
  float* dl = p;  p += (size_t)BLq*256;
  float* bc = p;  p += (size_t)BLq*32;
  float* y  = p;  p += (size_t)BLq*256;
  float* sf = p;  p += (size_t)Bq*NCq*256*16;
  float* sd = p;  p += (size_t)Bq*NCq*256;
  float* si = p;  p += (size_t)Bq*NCq*256*16;

  k_embed<<<BLq, 128, 0, stream>>>(x, Wem, bem, h);
  for (int layer=0; layer<4; ++layer){
    k_gemm_bt<<<dim3(128,8), 256, 0, stream>>>(h, inw + (size_t)layer*512*128, xz, BLq, 512, 128);
    k_conv<<<BLq, 256, 0, stream>>>(xz, cw + (size_t)layer*256*4, cb + (size_t)layer*256, u);
    k_xdbl<<<BLq, 64, 0, stream>>>(u, xpw + (size_t)layer*40*256, dtw + (size_t)layer*256*8,
                                   dtb + (size_t)layer*256, dl, bc);
    k_scan_a<<<dim3(NCq,16,Bq), 256, 0, stream>>>(dl, u, bc, alog + (size_t)layer*4096, sf, sd);
    k_scan_b<<<64, 256, 0, stream>>>(sf, sd, alog + (size_t)layer*4096, si);
    k_scan_c<<<dim3(NCq,16,Bq), 256, 0, stream>>>(dl, u, bc, xz, si, alog + (size_t)layer*4096,
                                                  dsk + (size_t)layer*256, y);
    k_gemm_bt<<<dim3(128,2), 256, 0, stream>>>(y, outw + (size_t)layer*128*256, h, BLq, 128, 256);
  }
  k_pool<<<Bq, 1024, 0, stream>>>(h, Wl, bl_, out);
}

// Round 4
// 735.902 us; speedup vs baseline: 1.3517x; 1.3517x over previous
//
#include <hip/hip_runtime.h>
#include <math.h>

// Problem constants
#define Bq 4
#define Lq 2048
#define BLq 8192          // B*L
#define DMq 128           // d_model
#define DIq 256           // d_inner
#define DSq 16            // d_state
#define NC2 32            // scan chunks
#define TC2 64            // chunk length (NC2*TC2 == Lq)

__device__ __forceinline__ float siluf(float x){ return x / (1.f + expf(-x)); }
__device__ __forceinline__ float softplusf(float x){
  return (x > 0.f) ? (x + log1pf(expf(-x))) : log1pf(expf(x));
}

// h[bl,e] = sum_k x[bl,k]*W[k,e] + b[e]   (K=64, N=128)
__global__ __launch_bounds__(128) void k_embed(const float* __restrict__ x,
    const float* __restrict__ W, const float* __restrict__ bb, float* __restrict__ h){
  int bl = blockIdx.x; int e = threadIdx.x;
  __shared__ float xs[64];
  if (e < 64) xs[e] = x[(size_t)bl*64 + e];
  __syncthreads();
  float acc = bb[e];
  #pragma unroll
  for (int k=0;k<64;k++) acc = fmaf(xs[k], W[k*128 + e], acc);
  h[(size_t)bl*128 + e] = acc;
}

// C[M,N] = A[M,K] @ W[N,K]^T. BM=BN=64, BK=16, 256 thr, 4x4 per thread.
__global__ __launch_bounds__(256) void k_gemm_bt(const float* __restrict__ A,
    const float* __restrict__ W, float* __restrict__ C, int M, int N, int K){
  __shared__ float As[16][68];
  __shared__ float Ws[16][68];
  const int tid = threadIdx.x;
  const int tx = tid & 15, ty = tid >> 4;
  const int lr = tid >> 2, lc = (tid & 3) << 2;
  const int m0 = blockIdx.x << 6, n0 = blockIdx.y << 6;
  float acc[4][4] = {};
  for (int k0 = 0; k0 < K; k0 += 16){
    float4 av = *(const float4*)(A + (size_t)(m0+lr)*K + k0 + lc);
    float4 wv = *(const float4*)(W + (size_t)(n0+lr)*K + k0 + lc);
    As[lc+0][lr]=av.x; As[lc+1][lr]=av.y; As[lc+2][lr]=av.z; As[lc+3][lr]=av.w;
    Ws[lc+0][lr]=wv.x; Ws[lc+1][lr]=wv.y; Ws[lc+2][lr]=wv.z; Ws[lc+3][lr]=wv.w;
    __syncthreads();
    #pragma unroll
    for (int k=0;k<16;k++){
      float4 a = *(const float4*)&As[k][ty<<2];
      float4 w = *(const float4*)&Ws[k][tx<<2];
      acc[0][0]=fmaf(a.x,w.x,acc[0][0]); acc[0][1]=fmaf(a.x,w.y,acc[0][1]);
      acc[0][2]=fmaf(a.x,w.z,acc[0][2]); acc[0][3]=fmaf(a.x,w.w,acc[0][3]);
      acc[1][0]=fmaf(a.y,w.x,acc[1][0]); acc[1][1]=fmaf(a.y,w.y,acc[1][1]);
      acc[1][2]=fmaf(a.y,w.z,acc[1][2]); acc[1][3]=fmaf(a.y,w.w,acc[1][3]);
      acc[2][0]=fmaf(a.z,w.x,acc[2][0]); acc[2][1]=fmaf(a.z,w.y,acc[2][1]);
      acc[2][2]=fmaf(a.z,w.z,acc[2][2]); acc[2][3]=fmaf(a.z,w.w,acc[2][3]);
      acc[3][0]=fmaf(a.w,w.x,acc[3][0]); acc[3][1]=fmaf(a.w,w.y,acc[3][1]);
      acc[3][2]=fmaf(a.w,w.z,acc[3][2]); acc[3][3]=fmaf(a.w,w.w,acc[3][3]);
    }
    __syncthreads();
  }
  #pragma unroll
  for (int i=0;i<4;i++){
    float4 o = make_float4(acc[i][0],acc[i][1],acc[i][2],acc[i][3]);
    *(float4*)(C + (size_t)(m0+(ty<<2)+i)*N + n0 + (tx<<2)) = o;
  }
}

// causal depthwise conv (D_CONV=4) over u-half of xz, then SiLU -> u
__global__ __launch_bounds__(256) void k_conv(const float* __restrict__ xz,
    const float* __restrict__ cw, const float* __restrict__ cb, float* __restrict__ u){
  int bl = blockIdx.x; int l = bl & 2047; int d = threadIdx.x;
  float4 w = *(const float4*)(cw + d*4);
  float wv[4] = {w.x, w.y, w.z, w.w};
  const float* base = xz + (size_t)bl*512 + d;
  float acc = cb[d];
  #pragma unroll
  for (int j=0;j<4;j++){
    if (l-3+j >= 0) acc = fmaf(base[(j-3)*512], wv[j], acc);
  }
  u[(size_t)bl*256 + d] = siluf(acc);
}

// per (b,l): x_dbl[40] = u_row @ xp_w^T ; delta=softplus(x_dbl[:8]@dt_w^T+dt_b)
__global__ __launch_bounds__(64) void k_xdbl(const float* __restrict__ u,
    const float* __restrict__ xpw, const float* __restrict__ dtw,
    const float* __restrict__ dtb, float* __restrict__ dlt, float* __restrict__ bc){
  int bl = blockIdx.x; int tid = threadIdx.x;
  int g = tid >> 3, i = tid & 7;
  float4 us[8];
  #pragma unroll
  for (int j=0;j<8;j++) us[j] = *(const float4*)(u + (size_t)bl*256 + i*32 + j*4);
  __shared__ float xd[40];
  #pragma unroll
  for (int q=0;q<5;q++){
    int e = g*5 + q;
    const float* wp = xpw + e*256 + i*32;
    float p = 0.f;
    #pragma unroll
    for (int j=0;j<8;j++){
      float4 w = *(const float4*)(wp + j*4);
      p = fmaf(us[j].x,w.x,p); p = fmaf(us[j].y,w.y,p);
      p = fmaf(us[j].z,w.z,p); p = fmaf(us[j].w,w.w,p);
    }
    p += __shfl_xor(p,1); p += __shfl_xor(p,2); p += __shfl_xor(p,4);
    if (i==0) xd[e] = p;
  }
  __syncthreads();
  if (tid < 32) bc[(size_t)bl*32 + tid] = xd[8+tid];
  float xr[8];
  #pragma unroll
  for (int r=0;r<8;r++) xr[r] = xd[r];
  float o4[4];
  #pragma unroll
  for (int c=0;c<4;c++){
    int d = tid*4 + c;
    float acc = dtb[d];
    const float* wp = dtw + d*8;
    #pragma unroll
    for (int r=0;r<8;r++) acc = fmaf(xr[r], wp[r], acc);
    o4[c] = softplusf(acc);
  }
  *(float4*)(dlt + (size_t)bl*256 + tid*4) = make_float4(o4[0],o4[1],o4[2],o4[3]);
}

// ---------------- scan: LDS-staged, thread = (d, 4 n-states) ----------------
// grid (NC2, 8 d-groups of 32, B), block 128 (2 waves x [16 d | 4 nq])

__global__ __launch_bounds__(128) void k_scan_a2(const float* __restrict__ dlt,
    const float* __restrict__ u, const float* __restrict__ bc,
    const float* __restrict__ alog, float* __restrict__ sf, float* __restrict__ sd){
  __shared__ float ds_[TC2*32], us_[TC2*32], bs_[TC2*16];
  const int tid = threadIdx.x;
  const int c = blockIdx.x, dg = blockIdx.y, b = blockIdx.z;
  const size_t row0 = (size_t)b*Lq + (size_t)c*TC2;
  {
    const float* dbase = dlt + row0*256 + dg*32;
    const float* ubase = u   + row0*256 + dg*32;
    #pragma unroll
    for (int k=0;k<4;k++){              // 512 quads: 64 rows x 8 quads
      int q = tid + k*128;
      int r = q >> 3, c4 = (q & 7) << 2;
      *(float4*)&ds_[r*32 + c4] = *(const float4*)(dbase + (size_t)r*256 + c4);
      *(float4*)&us_[r*32 + c4] = *(const float4*)(ubase + (size_t)r*256 + c4);
    }
    const float* bbase = bc + row0*32;  // B half: 64 rows x 4 quads = 256 quads
    #pragma unroll
    for (int k=0;k<2;k++){
      int q = tid + k*128;
      int r = q >> 2, c4 = (q & 3) << 2;
      *(float4*)&bs_[r*16 + c4] = *(const float4*)(bbase + (size_t)r*32 + c4);
    }
  }
  __syncthreads();
  const int lane = tid & 63, w = tid >> 6;
  const int dloc = w*16 + (lane & 15);
  const int nq = (lane >> 4) & 3;
  const int d = dg*32 + dloc;
  float4 al = *(const float4*)(alog + d*16 + nq*4);
  float Av0 = -expf(al.x), Av1 = -expf(al.y), Av2 = -expf(al.z), Av3 = -expf(al.w);
  float s0=0.f,s1=0.f,s2=0.f,s3=0.f, sdl=0.f;
  for (int t=0;t<TC2;t++){
    float de = ds_[t*32 + dloc];
    float uu = us_[t*32 + dloc];
    float du = de*uu;
    float4 Bv = *(const float4*)&bs_[t*16 + (nq<<2)];
    s0 = fmaf(expf(de*Av0), s0, du*Bv.x);
    s1 = fmaf(expf(de*Av1), s1, du*Bv.y);
    s2 = fmaf(expf(de*Av2), s2, du*Bv.z);
    s3 = fmaf(expf(de*Av3), s3, du*Bv.w);
    sdl += de;
  }
  size_t idx = ((size_t)b*NC2 + c)*256 + d;
  *(float4*)(sf + idx*16 + (nq<<2)) = make_float4(s0,s1,s2,s3);
  if (nq==0) sd[idx] = sdl;
}

// combine chunk aggregates -> exclusive initial state per chunk
__global__ __launch_bounds__(256) void k_scan_b2(const float* __restrict__ sf,
    const float* __restrict__ sd, const float* __restrict__ alog, float* __restrict__ si){
  int b = blockIdx.x >> 4, dg = blockIdx.x & 15;
  int tid = threadIdx.x; int n = tid & 15, dl = tid >> 4; int d = dg*16 + dl;
  float Av = -expf(alog[d*16+n]);
  float s = 0.f;
  for (int c=0;c<NC2;c++){
    size_t idx = ((size_t)b*NC2 + c)*256 + d;
    si[idx*16+n] = s;
    s = sf[idx*16+n] + expf(Av * sd[idx]) * s;
  }
}

__global__ __launch_bounds__(128) void k_scan_c2(const float* __restrict__ dlt,
    const float* __restrict__ u, const float* __restrict__ bc,
    const float* __restrict__ xz, const float* __restrict__ si,
    const float* __restrict__ alog, const float* __restrict__ dsk, float* __restrict__ y){
  __shared__ float ds_[TC2*32], us_[TC2*32], bcs_[TC2*32], zs_[TC2*32], ys_[TC2*32];
  const int tid = threadIdx.x;
  const int c = blockIdx.x, dg = blockIdx.y, b = blockIdx.z;
  const size_t row0 = (size_t)b*Lq + (size_t)c*TC2;
  {
    const float* dbase = dlt + row0*256 + dg*32;
    const float* ubase = u   + row0*256 + dg*32;
    const float* zbase = xz  + row0*512 + 256 + dg*32;
    const float* bbase = bc  + row0*32;
    #pragma unroll
    for (int k=0;k<4;k++){
      int q = tid + k*128;
      int r = q >> 3, c4 = (q & 7) << 2;
      *(float4*)&ds_[r*32 + c4]  = *(const float4*)(dbase + (size_t)r*256 + c4);
      *(float4*)&us_[r*32 + c4]  = *(const float4*)(ubase + (size_t)r*256 + c4);
      *(float4*)&zs_[r*32 + c4]  = *(const float4*)(zbase + (size_t)r*512 + c4);
      *(float4*)&bcs_[r*32 + c4] = *(const float4*)(bbase + (size_t)r*32  + c4);
    }
  }
  __syncthreads();
  const int lane = tid & 63, w = tid >> 6;
  const int dloc = w*16 + (lane & 15);
  const int nq = (lane >> 4) & 3;
  const int d = dg*32 + dloc;
  float4 al = *(const float4*)(alog + d*16 + (nq<<2));
  float Av0 = -expf(al.x), Av1 = -expf(al.y), Av2 = -expf(al.z), Av3 = -expf(al.w);
  float Dv = dsk[d];
  size_t idx = ((size_t)b*NC2 + c)*256 + d;
  float4 sv = *(const float4*)(si + idx*16 + (nq<<2));
  float s0 = sv.x, s1 = sv.y, s2 = sv.z, s3 = sv.w;
  for (int t=0;t<TC2;t++){
    float de = ds_[t*32 + dloc];
    float uu = us_[t*32 + dloc];
    float du = de*uu;
    float4 Bv = *(const float4*)&bcs_[t*32 + (nq<<2)];
    float4 Cv = *(const float4*)&bcs_[t*32 + 16 + (nq<<2)];
    s0 = fmaf(expf(de*Av0), s0, du*Bv.x);
    s1 = fmaf(expf(de*Av1), s1, du*Bv.y);
    s2 = fmaf(expf(de*Av2), s2, du*Bv.z);
    s3 = fmaf(expf(de*Av3), s3, du*Bv.w);
    float py = s0*Cv.x + s1*Cv.y + s2*Cv.z + s3*Cv.w;
    py += __shfl_xor(py, 16);
    py += __shfl_xor(py, 32);
    if (nq==0){
      float zz = zs_[t*32 + dloc];
      ys_[t*32 + dloc] = fmaf(uu, Dv, py) * siluf(zz);
    }
  }
  __syncthreads();
  {
    float* ybase = y + row0*256 + dg*32;
    #pragma unroll
    for (int k=0;k<4;k++){
      int q = tid + k*128;
      int r = q >> 3, c4 = (q & 7) << 2;
      *(float4*)(ybase + (size_t)r*256 + c4) = *(const float4*)&ys_[r*32 + c4];
    }
  }
}

// mean over L then latent GEMV: out[b,:] = pooled @ W_lat + b_lat
__global__ __launch_bounds__(1024) void k_pool(const float* __restrict__ h,
    const float* __restrict__ Wl, const float* __restrict__ bl_, float* __restrict__ out){
  int b = blockIdx.x; int tid = threadIdx.x;
  int e = tid & 127, st = tid >> 7;
  float s = 0.f;
  for (int l = st*256; l < st*256 + 256; ++l) s += h[((size_t)b*2048 + l)*128 + e];
  __shared__ float part[8][128];
  __shared__ float pooled[128];
  part[st][e] = s;
  __syncthreads();
  if (tid < 128){
    float tot = 0.f;
    #pragma unroll
    for (int j=0;j<8;j++) tot += part[j][tid];
    pooled[tid] = tot * (1.f/2048.f);
  }
  __syncthreads();
  if (tid < 128){
    float acc = bl_[tid];
    for (int e2=0;e2<128;e2++) acc = fmaf(pooled[e2], Wl[e2*128 + tid], acc);
    out[b*128 + tid] = acc;
  }
}

extern "C" void kernel_launch(void* const* d_in, const int* in_sizes, int n_in,
                              void* d_out, int out_size, void* d_ws, size_t ws_size,
                              hipStream_t stream){
  const float* x    = (const float*)d_in[0];
  const float* Wem  = (const float*)d_in[1];
  const float* bem  = (const float*)d_in[2];
  const float* inw  = (const float*)d_in[3];
  const float* cw   = (const float*)d_in[4];
  const float* cb   = (const float*)d_in[5];
  const float* xpw  = (const float*)d_in[6];
  const float* dtw  = (const float*)d_in[7];
  const float* dtb  = (const float*)d_in[8];
  const float* alog = (const float*)d_in[9];
  const float* dsk  = (const float*)d_in[10];
  const float* outw = (const float*)d_in[11];
  const float* Wl   = (const float*)d_in[12];
  const float* bl_  = (const float*)d_in[13];
  float* out = (float*)d_out;

  float* p  = (float*)d_ws;
  float* h  = p;  p += (size_t)BLq*128;
  float* xz = p;  p += (size_t)BLq*512;
  float* u  = p;  p += (size_t)BLq*256;
  float* dl = p;  p += (size_t)BLq*256;
  float* bc = p;  p += (size_t)BLq*32;
  float* y  = p;  p += (size_t)BLq*256;
  float* sf = p;  p += (size_t)Bq*NC2*256*16;
  float* sd = p;  p += (size_t)Bq*NC2*256;
  float* si = p;  p += (size_t)Bq*NC2*256*16;

  k_embed<<<BLq, 128, 0, stream>>>(x, Wem, bem, h);
  for (int layer=0; layer<4; ++layer){
    k_gemm_bt<<<dim3(128,8), 256, 0, stream>>>(h, inw + (size_t)layer*512*128, xz, BLq, 512, 128);
    k_conv<<<BLq, 256, 0, stream>>>(xz, cw + (size_t)layer*256*4, cb + (size_t)layer*256, u);
    k_xdbl<<<BLq, 64, 0, stream>>>(u, xpw + (size_t)layer*40*256, dtw + (size_t)layer*256*8,
                                   dtb + (size_t)layer*256, dl, bc);
    k_scan_a2<<<dim3(NC2,8,Bq), 128, 0, stream>>>(dl, u, bc, alog + (size_t)layer*4096, sf, sd);
    k_scan_b2<<<64, 256, 0, stream>>>(sf, sd, alog + (size_t)layer*4096, si);
    k_scan_c2<<<dim3(NC2,8,Bq), 128, 0, stream>>>(dl, u, bc, xz, si, alog + (size_t)layer*4096,
                                                  dsk + (size_t)layer*256, y);
    k_gemm_bt<<<dim3(128,2), 256, 0, stream>>>(y, outw + (size_t)layer*128*256, h, BLq, 128, 256);
  }
  k_pool<<<Bq, 1024, 0, stream>>>(h, Wl, bl_, out);
}

// Round 5
// 617.397 us; speedup vs baseline: 1.6112x; 1.1919x over previous
//
#include <hip/hip_runtime.h>
#include <math.h>

// Problem constants
#define Bq 4
#define Lq 2048
#define BLq 8192          // B*L
#define DMq 128           // d_model
#define DIq 256           // d_inner
#define DSq 16            // d_state
#define NC2 32            // scan chunks
#define TC2 64            // chunk length (NC2*TC2 == Lq)

__device__ __forceinline__ float siluf(float x){ return x / (1.f + expf(-x)); }
__device__ __forceinline__ float softplusf(float x){
  return (x > 0.f) ? (x + log1pf(expf(-x))) : log1pf(expf(x));
}

// h[bl,e] = sum_k x[bl,k]*W[k,e] + b[e]   (K=64, N=128)
__global__ __launch_bounds__(128) void k_embed(const float* __restrict__ x,
    const float* __restrict__ W, const float* __restrict__ bb, float* __restrict__ h){
  int bl = blockIdx.x; int e = threadIdx.x;
  __shared__ float xs[64];
  if (e < 64) xs[e] = x[(size_t)bl*64 + e];
  __syncthreads();
  float acc = bb[e];
  #pragma unroll
  for (int k=0;k<64;k++) acc = fmaf(xs[k], W[k*128 + e], acc);
  h[(size_t)bl*128 + e] = acc;
}

// C[M,N] = A[M,K] @ W[N,K]^T. BM=BN=64, BK=16, 256 thr, 4x4 per thread.
__global__ __launch_bounds__(256) void k_gemm_bt(const float* __restrict__ A,
    const float* __restrict__ W, float* __restrict__ C, int M, int N, int K){
  __shared__ float As[16][68];
  __shared__ float Ws[16][68];
  const int tid = threadIdx.x;
  const int tx = tid & 15, ty = tid >> 4;
  const int lr = tid >> 2, lc = (tid & 3) << 2;
  const int m0 = blockIdx.x << 6, n0 = blockIdx.y << 6;
  float acc[4][4] = {};
  for (int k0 = 0; k0 < K; k0 += 16){
    float4 av = *(const float4*)(A + (size_t)(m0+lr)*K + k0 + lc);
    float4 wv = *(const float4*)(W + (size_t)(n0+lr)*K + k0 + lc);
    As[lc+0][lr]=av.x; As[lc+1][lr]=av.y; As[lc+2][lr]=av.z; As[lc+3][lr]=av.w;
    Ws[lc+0][lr]=wv.x; Ws[lc+1][lr]=wv.y; Ws[lc+2][lr]=wv.z; Ws[lc+3][lr]=wv.w;
    __syncthreads();
    #pragma unroll
    for (int k=0;k<16;k++){
      float4 a = *(const float4*)&As[k][ty<<2];
      float4 w = *(const float4*)&Ws[k][tx<<2];
      acc[0][0]=fmaf(a.x,w.x,acc[0][0]); acc[0][1]=fmaf(a.x,w.y,acc[0][1]);
      acc[0][2]=fmaf(a.x,w.z,acc[0][2]); acc[0][3]=fmaf(a.x,w.w,acc[0][3]);
      acc[1][0]=fmaf(a.y,w.x,acc[1][0]); acc[1][1]=fmaf(a.y,w.y,acc[1][1]);
      acc[1][2]=fmaf(a.y,w.z,acc[1][2]); acc[1][3]=fmaf(a.y,w.w,acc[1][3]);
      acc[2][0]=fmaf(a.z,w.x,acc[2][0]); acc[2][1]=fmaf(a.z,w.y,acc[2][1]);
      acc[2][2]=fmaf(a.z,w.z,acc[2][2]); acc[2][3]=fmaf(a.z,w.w,acc[2][3]);
      acc[3][0]=fmaf(a.w,w.x,acc[3][0]); acc[3][1]=fmaf(a.w,w.y,acc[3][1]);
      acc[3][2]=fmaf(a.w,w.z,acc[3][2]); acc[3][3]=fmaf(a.w,w.w,acc[3][3]);
    }
    __syncthreads();
  }
  #pragma unroll
  for (int i=0;i<4;i++){
    float4 o = make_float4(acc[i][0],acc[i][1],acc[i][2],acc[i][3]);
    *(float4*)(C + (size_t)(m0+(ty<<2)+i)*N + n0 + (tx<<2)) = o;
  }
}

// causal depthwise conv (D_CONV=4) over u-half of xz, then SiLU -> u
__global__ __launch_bounds__(256) void k_conv(const float* __restrict__ xz,
    const float* __restrict__ cw, const float* __restrict__ cb, float* __restrict__ u){
  int bl = blockIdx.x; int l = bl & 2047; int d = threadIdx.x;
  float4 w = *(const float4*)(cw + d*4);
  float wv[4] = {w.x, w.y, w.z, w.w};
  const float* base = xz + (size_t)bl*512 + d;
  float acc = cb[d];
  #pragma unroll
  for (int j=0;j<4;j++){
    if (l-3+j >= 0) acc = fmaf(base[(j-3)*512], wv[j], acc);
  }
  u[(size_t)bl*256 + d] = siluf(acc);
}

// pad xp_w [4][40][256] -> xdp [4][64][256] (rows 40..63 zero). grid 256, blk 256.
__global__ __launch_bounds__(256) void k_padw(const float* __restrict__ xpw,
    float* __restrict__ xdp){
  int blk = blockIdx.x; int layer = blk >> 6, e = blk & 63;
  int tid = threadIdx.x;
  float v = 0.f;
  if (e < 40) v = xpw[((size_t)layer*40 + e)*256 + tid];
  xdp[((size_t)layer*64 + e)*256 + tid] = v;
}

// xd[8192x64] = u[8192x256] @ xdp[64x256]^T. BM=32,BN=64,BK=32, 256 blocks.
__global__ __launch_bounds__(256) void k_xg(const float* __restrict__ u,
    const float* __restrict__ xdp, float* __restrict__ xd){
  __shared__ float As[32][34];   // [k][m], stride 34 (b64-aligned, 2-way max)
  __shared__ float Ws[32][68];   // [k][n], stride 68 (b128-aligned)
  const int tid = threadIdx.x;
  const int m0 = blockIdx.x << 5;
  const int tm = tid & 15, tn = tid >> 4;
  const int r = tid >> 3, c4 = (tid & 7) << 2;
  float acc[2][4] = {};
  for (int k0=0;k0<256;k0+=32){
    float4 av = *(const float4*)(u + (size_t)(m0+r)*256 + k0 + c4);
    As[c4+0][r]=av.x; As[c4+1][r]=av.y; As[c4+2][r]=av.z; As[c4+3][r]=av.w;
    #pragma unroll
    for (int p=0;p<2;p++){
      int q = tid + p*256;
      int n = q >> 3, wc = (q & 7) << 2;
      float4 wv = *(const float4*)(xdp + (size_t)n*256 + k0 + wc);
      Ws[wc+0][n]=wv.x; Ws[wc+1][n]=wv.y; Ws[wc+2][n]=wv.z; Ws[wc+3][n]=wv.w;
    }
    __syncthreads();
    #pragma unroll
    for (int k=0;k<32;k++){
      float2 a = *(const float2*)&As[k][tm<<1];
      float4 w = *(const float4*)&Ws[k][tn<<2];
      acc[0][0]=fmaf(a.x,w.x,acc[0][0]); acc[0][1]=fmaf(a.x,w.y,acc[0][1]);
      acc[0][2]=fmaf(a.x,w.z,acc[0][2]); acc[0][3]=fmaf(a.x,w.w,acc[0][3]);
      acc[1][0]=fmaf(a.y,w.x,acc[1][0]); acc[1][1]=fmaf(a.y,w.y,acc[1][1]);
      acc[1][2]=fmaf(a.y,w.z,acc[1][2]); acc[1][3]=fmaf(a.y,w.w,acc[1][3]);
    }
    __syncthreads();
  }
  #pragma unroll
  for (int i=0;i<2;i++){
    *(float4*)(xd + (size_t)(m0 + (tm<<1) + i)*64 + (tn<<2)) =
        make_float4(acc[i][0],acc[i][1],acc[i][2],acc[i][3]);
  }
}

// delta = softplus(xd[:, :8] @ dtw^T + dtb) -> dlt[8192x256]; bc = xd[:, 8:40]
__global__ __launch_bounds__(256) void k_delta(const float* __restrict__ xd,
    const float* __restrict__ dtw, const float* __restrict__ dtb,
    float* __restrict__ dlt, float* __restrict__ bc){
  __shared__ float wt[8][256];   // transposed dt_w
  __shared__ float xds[32][8];
  const int tid = threadIdx.x;
  const int row0 = blockIdx.x << 5;
  {
    float4 w0 = *(const float4*)(dtw + tid*8);
    float4 w1 = *(const float4*)(dtw + tid*8 + 4);
    wt[0][tid]=w0.x; wt[1][tid]=w0.y; wt[2][tid]=w0.z; wt[3][tid]=w0.w;
    wt[4][tid]=w1.x; wt[5][tid]=w1.y; wt[6][tid]=w1.z; wt[7][tid]=w1.w;
  }
  if (tid < 64){
    int rr = tid >> 1, cc = (tid & 1) << 2;
    *(float4*)&xds[rr][cc] = *(const float4*)(xd + (size_t)(row0+rr)*64 + cc);
  }
  __syncthreads();
  float bias = dtb[tid];
  for (int rr=0; rr<32; ++rr){
    float acc = bias;
    #pragma unroll
    for (int j=0;j<8;j++) acc = fmaf(xds[rr][j], wt[j][tid], acc);
    dlt[(size_t)(row0+rr)*256 + tid] = softplusf(acc);
  }
  #pragma unroll
  for (int k=0;k<4;k++){
    int idx = k*256 + tid;
    int rr = idx >> 5, cc = idx & 31;
    bc[(size_t)(row0+rr)*32 + cc] = xd[(size_t)(row0+rr)*64 + 8 + cc];
  }
}

// ---------------- scan: LDS-staged, thread = (d, 4 n-states) ----------------
// grid (NC2, 8 d-groups of 32, B), block 128 (2 waves x [16 d | 4 nq])

__global__ __launch_bounds__(128) void k_scan_a2(const float* __restrict__ dlt,
    const float* __restrict__ u, const float* __restrict__ bc,
    const float* __restrict__ alog, float* __restrict__ sf, float* __restrict__ sd){
  __shared__ float ds_[TC2*32], us_[TC2*32], bs_[TC2*16];
  const int tid = threadIdx.x;
  const int c = blockIdx.x, dg = blockIdx.y, b = blockIdx.z;
  const size_t row0 = (size_t)b*Lq + (size_t)c*TC2;
  {
    const float* dbase = dlt + row0*256 + dg*32;
    const float* ubase = u   + row0*256 + dg*32;
    #pragma unroll
    for (int k=0;k<4;k++){
      int q = tid + k*128;
      int r = q >> 3, c4 = (q & 7) << 2;
      *(float4*)&ds_[r*32 + c4] = *(const float4*)(dbase + (size_t)r*256 + c4);
      *(float4*)&us_[r*32 + c4] = *(const float4*)(ubase + (size_t)r*256 + c4);
    }
    const float* bbase = bc + row0*32;
    #pragma unroll
    for (int k=0;k<2;k++){
      int q = tid + k*128;
      int r = q >> 2, c4 = (q & 3) << 2;
      *(float4*)&bs_[r*16 + c4] = *(const float4*)(bbase + (size_t)r*32 + c4);
    }
  }
  __syncthreads();
  const int lane = tid & 63, w = tid >> 6;
  const int dloc = w*16 + (lane & 15);
  const int nq = (lane >> 4) & 3;
  const int d = dg*32 + dloc;
  float4 al = *(const float4*)(alog + d*16 + nq*4);
  float Av0 = -expf(al.x), Av1 = -expf(al.y), Av2 = -expf(al.z), Av3 = -expf(al.w);
  float s0=0.f,s1=0.f,s2=0.f,s3=0.f, sdl=0.f;
  for (int t=0;t<TC2;t++){
    float de = ds_[t*32 + dloc];
    float uu = us_[t*32 + dloc];
    float du = de*uu;
    float4 Bv = *(const float4*)&bs_[t*16 + (nq<<2)];
    s0 = fmaf(expf(de*Av0), s0, du*Bv.x);
    s1 = fmaf(expf(de*Av1), s1, du*Bv.y);
    s2 = fmaf(expf(de*Av2), s2, du*Bv.z);
    s3 = fmaf(expf(de*Av3), s3, du*Bv.w);
    sdl += de;
  }
  size_t idx = ((size_t)b*NC2 + c)*256 + d;
  *(float4*)(sf + idx*16 + (nq<<2)) = make_float4(s0,s1,s2,s3);
  if (nq==0) sd[idx] = sdl;
}

// combine chunk aggregates -> exclusive initial state per chunk
__global__ __launch_bounds__(256) void k_scan_b2(const float* __restrict__ sf,
    const float* __restrict__ sd, const float* __restrict__ alog, float* __restrict__ si){
  int b = blockIdx.x >> 4, dg = blockIdx.x & 15;
  int tid = threadIdx.x; int n = tid & 15, dl = tid >> 4; int d = dg*16 + dl;
  float Av = -expf(alog[d*16+n]);
  float s = 0.f;
  for (int c=0;c<NC2;c++){
    size_t idx = ((size_t)b*NC2 + c)*256 + d;
    si[idx*16+n] = s;
    s = sf[idx*16+n] + expf(Av * sd[idx]) * s;
  }
}

__global__ __launch_bounds__(128) void k_scan_c2(const float* __restrict__ dlt,
    const float* __restrict__ u, const float* __restrict__ bc,
    const float* __restrict__ xz, const float* __restrict__ si,
    const float* __restrict__ alog, const float* __restrict__ dsk, float* __restrict__ y){
  __shared__ float ds_[TC2*32], us_[TC2*32], bcs_[TC2*32], zs_[TC2*32], ys_[TC2*32];
  const int tid = threadIdx.x;
  const int c = blockIdx.x, dg = blockIdx.y, b = blockIdx.z;
  const size_t row0 = (size_t)b*Lq + (size_t)c*TC2;
  {
    const float* dbase = dlt + row0*256 + dg*32;
    const float* ubase = u   + row0*256 + dg*32;
    const float* zbase = xz  + row0*512 + 256 + dg*32;
    const float* bbase = bc  + row0*32;
    #pragma unroll
    for (int k=0;k<4;k++){
      int q = tid + k*128;
      int r = q >> 3, c4 = (q & 7) << 2;
      *(float4*)&ds_[r*32 + c4]  = *(const float4*)(dbase + (size_t)r*256 + c4);
      *(float4*)&us_[r*32 + c4]  = *(const float4*)(ubase + (size_t)r*256 + c4);
      *(float4*)&zs_[r*32 + c4]  = *(const float4*)(zbase + (size_t)r*512 + c4);
      *(float4*)&bcs_[r*32 + c4] = *(const float4*)(bbase + (size_t)r*32  + c4);
    }
  }
  __syncthreads();
  const int lane = tid & 63, w = tid >> 6;
  const int dloc = w*16 + (lane & 15);
  const int nq = (lane >> 4) & 3;
  const int d = dg*32 + dloc;
  float4 al = *(const float4*)(alog + d*16 + (nq<<2));
  float Av0 = -expf(al.x), Av1 = -expf(al.y), Av2 = -expf(al.z), Av3 = -expf(al.w);
  float Dv = dsk[d];
  size_t idx = ((size_t)b*NC2 + c)*256 + d;
  float4 sv = *(const float4*)(si + idx*16 + (nq<<2));
  float s0 = sv.x, s1 = sv.y, s2 = sv.z, s3 = sv.w;
  for (int t=0;t<TC2;t++){
    float de = ds_[t*32 + dloc];
    float uu = us_[t*32 + dloc];
    float du = de*uu;
    float4 Bv = *(const float4*)&bcs_[t*32 + (nq<<2)];
    float4 Cv = *(const float4*)&bcs_[t*32 + 16 + (nq<<2)];
    s0 = fmaf(expf(de*Av0), s0, du*Bv.x);
    s1 = fmaf(expf(de*Av1), s1, du*Bv.y);
    s2 = fmaf(expf(de*Av2), s2, du*Bv.z);
    s3 = fmaf(expf(de*Av3), s3, du*Bv.w);
    float py = s0*Cv.x + s1*Cv.y + s2*Cv.z + s3*Cv.w;
    py += __shfl_xor(py, 16);
    py += __shfl_xor(py, 32);
    if (nq==0){
      float zz = zs_[t*32 + dloc];
      ys_[t*32 + dloc] = fmaf(uu, Dv, py) * siluf(zz);
    }
  }
  __syncthreads();
  {
    float* ybase = y + row0*256 + dg*32;
    #pragma unroll
    for (int k=0;k<4;k++){
      int q = tid + k*128;
      int r = q >> 3, c4 = (q & 7) << 2;
      *(float4*)(ybase + (size_t)r*256 + c4) = *(const float4*)&ys_[r*32 + c4];
    }
  }
}

// mean over L then latent GEMV: out[b,:] = pooled @ W_lat + b_lat
__global__ __launch_bounds__(1024) void k_pool(const float* __restrict__ h,
    const float* __restrict__ Wl, const float* __restrict__ bl_, float* __restrict__ out){
  int b = blockIdx.x; int tid = threadIdx.x;
  int e = tid & 127, st = tid >> 7;
  float s = 0.f;
  for (int l = st*256; l < st*256 + 256; ++l) s += h[((size_t)b*2048 + l)*128 + e];
  __shared__ float part[8][128];
  __shared__ float pooled[128];
  part[st][e] = s;
  __syncthreads();
  if (tid < 128){
    float tot = 0.f;
    #pragma unroll
    for (int j=0;j<8;j++) tot += part[j][tid];
    pooled[tid] = tot * (1.f/2048.f);
  }
  __syncthreads();
  if (tid < 128){
    float acc = bl_[tid];
    for (int e2=0;e2<128;e2++) acc = fmaf(pooled[e2], Wl[e2*128 + tid], acc);
    out[b*128 + tid] = acc;
  }
}

extern "C" void kernel_launch(void* const* d_in, const int* in_sizes, int n_in,
                              void* d_out, int out_size, void* d_ws, size_t ws_size,
                              hipStream_t stream){
  const float* x    = (const float*)d_in[0];
  const float* Wem  = (const float*)d_in[1];
  const float* bem  = (const float*)d_in[2];
  const float* inw  = (const float*)d_in[3];
  const float* cw   = (const float*)d_in[4];
  const float* cb   = (const float*)d_in[5];
  const float* xpw  = (const float*)d_in[6];
  const float* dtw  = (const float*)d_in[7];
  const float* dtb  = (const float*)d_in[8];
  const float* alog = (const float*)d_in[9];
  const float* dsk  = (const float*)d_in[10];
  const float* outw = (const float*)d_in[11];
  const float* Wl   = (const float*)d_in[12];
  const float* bl_  = (const float*)d_in[13];
  float* out = (float*)d_out;

  float* p  = (float*)d_ws;
  float* h  = p;  p += (size_t)BLq*128;
  float* xz = p;  p += (size_t)BLq*512;
  float* u  = p;  p += (size_t)BLq*256;
  float* dl = p;  p += (size_t)BLq*256;
  float* bc = p;  p += (size_t)BLq*32;
  float* y  = p;  p += (size_t)BLq*256;
  float* sf = p;  p += (size_t)Bq*NC2*256*16;
  float* sd = p;  p += (size_t)Bq*NC2*256;
  float* si = p;  p += (size_t)Bq*NC2*256*16;
  float* xdp= p;  p += (size_t)4*64*256;
  float* xd = p;  p += (size_t)BLq*64;

  k_padw<<<256, 256, 0, stream>>>(xpw, xdp);
  k_embed<<<BLq, 128, 0, stream>>>(x, Wem, bem, h);
  for (int layer=0; layer<4; ++layer){
    k_gemm_bt<<<dim3(128,8), 256, 0, stream>>>(h, inw + (size_t)layer*512*128, xz, BLq, 512, 128);
    k_conv<<<BLq, 256, 0, stream>>>(xz, cw + (size_t)layer*256*4, cb + (size_t)layer*256, u);
    k_xg<<<256, 256, 0, stream>>>(u, xdp + (size_t)layer*64*256, xd);
    k_delta<<<256, 256, 0, stream>>>(xd, dtw + (size_t)layer*256*8, dtb + (size_t)layer*256,
                                     dl, bc);
    k_scan_a2<<<dim3(NC2,8,Bq), 128, 0, stream>>>(dl, u, bc, alog + (size_t)layer*4096, sf, sd);
    k_scan_b2<<<64, 256, 0, stream>>>(sf, sd, alog + (size_t)layer*4096, si);
    k_scan_c2<<<dim3(NC2,8,Bq), 128, 0, stream>>>(dl, u, bc, xz, si, alog + (size_t)layer*4096,
                                                  dsk + (size_t)layer*256, y);
    k_gemm_bt<<<dim3(128,2), 256, 0, stream>>>(y, outw + (size_t)layer*128*256, h, BLq, 128, 256);
  }
  k_pool<<<Bq, 1024, 0, stream>>>(h, Wl, bl_, out);
}